// Round 1
// baseline (435.181 us; speedup 1.0000x reference)
//
#include <hip/hip_runtime.h>
#include <math.h>

#define NN 1000

// ---------------- workspace float offsets ----------------
#define WS_H1P 0
#define WS_H1T 1024
#define WS_H2P 2048
#define WS_H2T 3072
#define WS_TS  4096
#define WS_XI  5120
#define WS_B1  8192
#define WS_B2  (8192 + 262144)
#define WS_VAR (8192 + 2*262144)

// ---------------- output float offsets ----------------
#define O_X0    0
#define O_STEP  256000
#define O_EPS   511744
#define O_VAR   512000
#define O_TS    768000
#define O_ALPHA 1024000
#define O_BETA  1024256
#define O_POWR  1024512

// ================= small MLPs (batch 1) =================
__global__ __launch_bounds__(256) void k_mlp_l1(const float* __restrict__ in,
    const float* __restrict__ W, const float* __restrict__ bias, float* __restrict__ h1)
{
    __shared__ float sin_[64];
    if (threadIdx.x < 64) sin_[threadIdx.x] = in[threadIdx.x];
    __syncthreads();
    int u = blockIdx.x * 256 + threadIdx.x;
    float acc = bias[u];
    #pragma unroll 16
    for (int k = 0; k < 64; ++k) acc += sin_[k] * W[k * 1024 + u];
    h1[u] = fmaxf(acc, 0.f);
}

__global__ __launch_bounds__(256) void k_mlp_l2(const float* __restrict__ h1,
    const float* __restrict__ W, const float* __restrict__ bias, float* __restrict__ h2)
{
    int tid = threadIdx.x;
    int c = tid >> 6, ul = tid & 63;
    int u = blockIdx.x * 64 + ul;
    float acc = 0.f;
    int k0 = c * 256;
    #pragma unroll 8
    for (int k = 0; k < 256; ++k) acc += h1[k0 + k] * W[(k0 + k) * 1024 + u];
    __shared__ float red[4][64];
    red[c][ul] = acc;
    __syncthreads();
    if (c == 0) {
        float v = red[0][ul] + red[1][ul] + red[2][ul] + red[3][ul] + bias[u];
        h2[u] = fmaxf(v, 0.f);
    }
}

// block 16: xi head (3 outputs + sigmoid + broadcast scalars); blocks 0..15: ts head
__global__ __launch_bounds__(256) void k_mlp_l3(const float* __restrict__ h2p,
    const float* __restrict__ pw3, const float* __restrict__ pb3,
    const float* __restrict__ h2t, const float* __restrict__ tw3, const float* __restrict__ tb3,
    float* __restrict__ ws, float* __restrict__ out)
{
    int tid = threadIdx.x;
    if (blockIdx.x == 16) {
        float p[3] = {0.f, 0.f, 0.f};
        for (int k = tid; k < 1024; k += 256) {
            float h = h2p[k];
            p[0] += h * pw3[k * 3 + 0];
            p[1] += h * pw3[k * 3 + 1];
            p[2] += h * pw3[k * 3 + 2];
        }
        __shared__ float red[256];
        float xi[3];
        #pragma unroll
        for (int j = 0; j < 3; ++j) {
            red[tid] = p[j]; __syncthreads();
            for (int s = 128; s > 0; s >>= 1) {
                if (tid < s) red[tid] += red[tid + s];
                __syncthreads();
            }
            xi[j] = red[0] + pb3[j];
            __syncthreads();
        }
        float alpha = xi[0], beta = xi[1];
        float powr = 1.f / (1.f + expf(-xi[2]));
        if (tid == 0) { ws[WS_XI + 0] = alpha; ws[WS_XI + 1] = beta; ws[WS_XI + 2] = powr; }
        out[O_ALPHA + tid] = alpha;
        out[O_BETA  + tid] = beta;
        out[O_POWR  + tid] = powr;
    } else {
        int c = tid >> 6, ul = tid & 63;
        int u = blockIdx.x * 64 + ul;
        float acc = 0.f;
        int k0 = c * 256;
        if (u < NN) {
            #pragma unroll 8
            for (int k = 0; k < 256; ++k) acc += h2t[k0 + k] * tw3[(k0 + k) * NN + u];
        }
        __shared__ float red[4][64];
        red[c][ul] = acc;
        __syncthreads();
        if (c == 0 && u < NN)
            ws[WS_TS + u] = red[0][ul] + red[1][ul] + red[2][ul] + red[3][ul] + tb3[u];
    }
}

// ================= f32 GEMM: C = act(A@B + bias), A:MxK(lda), B:KxN(row-major, stride N) =================
template <bool RELU>
__global__ __launch_bounds__(256) void k_gemm(const float* __restrict__ A,
    const float* __restrict__ B, const float* __restrict__ bias, float* __restrict__ C,
    int M, int K, int N, int lda, int ldc)
{
    __shared__ float As[16][33];
    __shared__ float Bs[16][64];
    int tid = threadIdx.x;
    int tx = tid & 15, ty = tid >> 4;
    int n0 = blockIdx.x * 64, m0 = blockIdx.y * 32;
    float acc[2][4] = {};
    for (int k0 = 0; k0 < K; k0 += 16) {
        #pragma unroll
        for (int p = 0; p < 2; ++p) {                // A tile 32x16
            int idx = p * 256 + tid;
            int kk = idx & 15, m = idx >> 4;
            int kg = k0 + kk;
            float v = (kg < K) ? A[(m0 + m) * lda + kg] : 0.f;
            As[kk][m] = v;
        }
        #pragma unroll
        for (int p = 0; p < 4; ++p) {                // B tile 16x64
            int idx = p * 256 + tid;
            int n = idx & 63, kk = idx >> 6;
            int kg = k0 + kk, ng = n0 + n;
            float v = (kg < K && ng < N) ? B[kg * N + ng] : 0.f;
            Bs[kk][n] = v;
        }
        __syncthreads();
        float t_[2][4] = {};                         // per-tile partial (better rounding)
        #pragma unroll
        for (int kk = 0; kk < 16; ++kk) {
            float a0 = As[kk][ty * 2], a1 = As[kk][ty * 2 + 1];
            float b0 = Bs[kk][tx * 4 + 0], b1 = Bs[kk][tx * 4 + 1];
            float b2 = Bs[kk][tx * 4 + 2], b3 = Bs[kk][tx * 4 + 3];
            t_[0][0] += a0 * b0; t_[0][1] += a0 * b1; t_[0][2] += a0 * b2; t_[0][3] += a0 * b3;
            t_[1][0] += a1 * b0; t_[1][1] += a1 * b1; t_[1][2] += a1 * b2; t_[1][3] += a1 * b3;
        }
        #pragma unroll
        for (int r = 0; r < 2; ++r)
            #pragma unroll
            for (int c = 0; c < 4; ++c) acc[r][c] += t_[r][c];
        __syncthreads();
    }
    #pragma unroll
    for (int r = 0; r < 2; ++r) {
        int row = m0 + ty * 2 + r;
        #pragma unroll
        for (int c = 0; c < 4; ++c) {
            int col = n0 + tx * 4 + c;
            if (col < N) {
                float v = acc[r][c] + bias[col];
                if (RELU) v = fmaxf(v, 0.f);
                C[row * ldc + col] = v;
            }
        }
    }
}

// ================= ODE solve helpers (block = 1 batch, 256 thr x 4 elems, f64) =================
__device__ inline void d_shift_left(const double a[4], double b4[4], double* sh, int tid, double pad)
{
    __syncthreads();
    sh[tid] = a[0];
    __syncthreads();
    b4[0] = a[1]; b4[1] = a[2]; b4[2] = a[3];
    b4[3] = (tid < 255) ? sh[tid + 1] : pad;
}
__device__ inline void d_shift_right(const double a[4], double b4[4], double* sh, int tid, double pad)
{
    __syncthreads();
    sh[tid] = a[3];
    __syncthreads();
    b4[1] = a[0]; b4[2] = a[1]; b4[3] = a[2];
    b4[0] = (tid > 0) ? sh[tid - 1] : pad;
}
__device__ inline void d_scan_fwd(const double a[4], double incl[4], double* swt, int tid)
{
    double p0 = a[0], p1 = p0 + a[1], p2 = p1 + a[2], p3 = p2 + a[3];
    int lane = tid & 63, wid = tid >> 6;
    double w = p3;
    #pragma unroll
    for (int d = 1; d < 64; d <<= 1) {
        double t = __shfl_up(w, d, 64);
        if (lane >= d) w += t;
    }
    __syncthreads();
    if (lane == 63) swt[wid] = w;
    __syncthreads();
    double off = w - p3;
    #pragma unroll
    for (int q = 0; q < 3; ++q) if (q < wid) off += swt[q];
    incl[0] = p0 + off; incl[1] = p1 + off; incl[2] = p2 + off; incl[3] = p3 + off;
}
__device__ inline void d_scan_rev(const double a[4], double incl[4], double* swt, int tid)
{
    double s3 = a[3], s2 = s3 + a[2], s1 = s2 + a[1], s0 = s1 + a[0];
    int lane = tid & 63, wid = tid >> 6;
    double w = s0;
    #pragma unroll
    for (int d = 1; d < 64; d <<= 1) {
        double t = __shfl_down(w, d, 64);
        if (lane < 64 - d) w += t;
    }
    __syncthreads();
    if (lane == 0) swt[wid] = w;
    __syncthreads();
    double off = w - s0;
    #pragma unroll
    for (int q = 1; q < 4; ++q) if (q > wid) off += swt[q];
    incl[0] = s0 + off; incl[1] = s1 + off; incl[2] = s2 + off; incl[3] = s3 + off;
}

// u_reg = u_ex - eps*(M+eps I)^-1 u_ex via Horner/Neumann; M^+ = two causal sweeps (cumsums).
__global__ __launch_bounds__(256) void k_ode(const float* __restrict__ ws, float* __restrict__ out)
{
    const int b = blockIdx.x;
    const int tid = threadIdx.x;
    const double H = 0.001, H2c = 0.5e-6, INVH = 1000.0, EPSR = 1e-8;

    __shared__ double sh[257];
    __shared__ double swt[4];

    const float alpha = ws[WS_XI + 0], beta = ws[WS_XI + 1], powr = ws[WS_XI + 2];

    const float4 tsv = *(const float4*)&ws[WS_TS + tid * 4];
    const float4 vav = *(const float4*)&ws[WS_VAR + b * 1024 + tid * 4];
    const double init = (double)ws[WS_VAR + b * 1024];

    float tsa[4] = {tsv.x, tsv.y, tsv.z, tsv.w};
    float vaa[4] = {vav.x, vav.y, vav.z, vav.w};

    // rhs (f32, mirroring jax) -> f64
    double r[4];
    #pragma unroll
    for (int k = 0; k < 4; ++k) {
        int i = tid * 4 + k;
        float tf = tsa[k], vf = vaa[k];
        float basef = fabsf(alpha * tf + beta * tf * tf);
        float rr = powf(basef, powr) * vf * vf + tf;
        r[k] = (i < NN) ? (double)rr : 0.0;
    }

    // exact min-norm solution u_ex
    double rn[4];
    d_shift_left(r, rn, sh, tid, 0.0);
    double ux[4], ud[4], us[4], g[4], gi[4];
    #pragma unroll
    for (int k = 0; k < 4; ++k) {
        int i = tid * 4 + k;
        ud[k] = r[k];
        us[k] = (i < NN - 1) ? (rn[k] - r[k]) * INVH : 0.0;
        g[k]  = (i < NN - 1) ? 0.5 * H * (r[k] + rn[k]) : 0.0;
    }
    d_scan_fwd(g, gi, swt, tid);
    #pragma unroll
    for (int k = 0; k < 4; ++k) {
        int i = tid * 4 + k;
        ux[k] = (i < NN) ? (init + (gi[k] - g[k])) : 0.0;   // exclusive scan
    }

    // Horner: t <- M^+ (u - eps*t), 8 terms
    double tx[4] = {0,0,0,0}, td[4] = {0,0,0,0}, tss[4] = {0,0,0,0};
    for (int it = 0; it < 8; ++it) {
        double a[4];
        #pragma unroll
        for (int k = 0; k < 4; ++k) {
            int i = tid * 4 + k;
            double yx = ux[k] - EPSR * tx[k];
            a[k] = (i == 0) ? 0.0 : yx;
        }
        double S[4]; d_scan_rev(a, S, swt, tid);
        double wP[4]; d_shift_left(S, wP, sh, tid, 0.0);    // wP_j = sum_{i>j} yx_i
        __syncthreads();
        if (tid == 0) sh[256] = (ux[0] - EPSR * tx[0]) + wP[0];
        __syncthreads();
        double w0 = sh[256];
        double wV[4];
        #pragma unroll
        for (int k = 0; k < 4; ++k) {
            int i = tid * 4 + k;
            double ys = us[k] - EPSR * tss[k];
            wV[k] = (i < NN - 1) ? -(ys + H2c * wP[k]) * INVH : 0.0;
        }
        double wVm[4]; d_shift_right(wV, wVm, sh, tid, 0.0);
        double wD[4];
        #pragma unroll
        for (int k = 0; k < 4; ++k) {
            int i = tid * 4 + k;
            double yd = ud[k] - EPSR * td[k];
            wD[k] = (i < NN) ? (yd + ((i < NN - 1) ? H * wP[k] : 0.0) - wVm[k] + wV[k]) : 0.0;
        }
        double wDn[4]; d_shift_left(wD, wDn, sh, tid, 0.0);
        #pragma unroll
        for (int k = 0; k < 4; ++k) {
            int i = tid * 4 + k;
            td[k]  = wD[k];
            tss[k] = (i < NN - 1) ? (wDn[k] - wD[k] - wV[k]) * INVH : 0.0;
            g[k]   = (i < NN - 1) ? (H * td[k] + H2c * tss[k] + wP[k]) : 0.0;
        }
        d_scan_fwd(g, gi, swt, tid);
        #pragma unroll
        for (int k = 0; k < 4; ++k) {
            int i = tid * 4 + k;
            tx[k] = (i < NN) ? (w0 + (gi[k] - g[k])) : 0.0;
        }
    }

    double dx[4], dd[4], ds_[4];
    #pragma unroll
    for (int k = 0; k < 4; ++k) { dx[k] = -EPSR * tx[k]; dd[k] = -EPSR * td[k]; ds_[k] = -EPSR * tss[k]; }

    // outputs
    #pragma unroll
    for (int k = 0; k < 4; ++k) {
        int i = tid * 4 + k;
        if (i < NN) {
            out[O_X0  + b * NN + i] = (float)(ux[k] + dx[k]);
            out[O_VAR + b * NN + i] = vaa[k];
            out[O_TS  + b * NN + i] = tsa[k];
        }
        if (i < NN - 1) out[O_STEP + b * (NN - 1) + i] = 0.001f;
    }
    if (tid == 0) { out[O_ALPHA + b] = alpha; out[O_BETA + b] = beta; out[O_POWR + b] = powr; }

    // eps = ||A u_reg - b|| = ||A * Delta||
    double dxn[4], ddn[4];
    d_shift_left(dx, dxn, sh, tid, 0.0);
    d_shift_left(dd, ddn, sh, tid, 0.0);
    double ss = 0.0;
    #pragma unroll
    for (int k = 0; k < 4; ++k) {
        int i = tid * 4 + k;
        if (i < NN) ss += dd[k] * dd[k];
        if (i == 0) ss += dx[k] * dx[k];
        if (i < NN - 1) {
            double rp = dxn[k] - dx[k] - H * dd[k] - H2c * ds_[k];
            double rv = ddn[k] - dd[k] - H * ds_[k];
            ss += rp * rp + rv * rv;
        }
    }
    __syncthreads();
    sh[tid] = ss;
    __syncthreads();
    for (int s = 128; s > 0; s >>= 1) {
        if (tid < s) sh[tid] += sh[tid + s];
        __syncthreads();
    }
    if (tid == 0) out[O_EPS + b] = (float)sqrt(sh[0]);
}

// ================= launcher =================
extern "C" void kernel_launch(void* const* d_in, const int* in_sizes, int n_in,
                              void* d_out, int out_size, void* d_ws, size_t ws_size,
                              hipStream_t stream)
{
    const float* pin    = (const float*)d_in[0];
    const float* ptime  = (const float*)d_in[1];
    const float* pw1    = (const float*)d_in[2];
    const float* pb1    = (const float*)d_in[3];
    const float* pw2    = (const float*)d_in[4];
    const float* pb2    = (const float*)d_in[5];
    const float* pw3    = (const float*)d_in[6];
    const float* pb3    = (const float*)d_in[7];
    const float* tw1    = (const float*)d_in[8];
    const float* tb1    = (const float*)d_in[9];
    const float* tw2    = (const float*)d_in[10];
    const float* tb2    = (const float*)d_in[11];
    const float* tw3    = (const float*)d_in[12];
    const float* tb3    = (const float*)d_in[13];
    const float* nw1    = (const float*)d_in[14];
    const float* nb1    = (const float*)d_in[15];
    const float* nw2    = (const float*)d_in[16];
    const float* nb2    = (const float*)d_in[17];
    const float* nw3    = (const float*)d_in[18];
    const float* nb3    = (const float*)d_in[19];
    const float* net_iv = (const float*)d_in[20];
    float* out = (float*)d_out;
    float* ws  = (float*)d_ws;

    // small MLPs (batch 1)
    k_mlp_l1<<<4, 256, 0, stream>>>(pin,   pw1, pb1, ws + WS_H1P);
    k_mlp_l1<<<4, 256, 0, stream>>>(ptime, tw1, tb1, ws + WS_H1T);
    k_mlp_l2<<<16, 256, 0, stream>>>(ws + WS_H1P, pw2, pb2, ws + WS_H2P);
    k_mlp_l2<<<16, 256, 0, stream>>>(ws + WS_H1T, tw2, tb2, ws + WS_H2T);
    k_mlp_l3<<<17, 256, 0, stream>>>(ws + WS_H2P, pw3, pb3, ws + WS_H2T, tw3, tb3, ws, out);

    // var MLP (batch 256), f32 GEMMs
    dim3 grd(16, 8);
    k_gemm<true ><<<grd, 256, 0, stream>>>(net_iv,     nw1, nb1, ws + WS_B1,  256, 1000, 1024, 1000, 1024);
    k_gemm<true ><<<grd, 256, 0, stream>>>(ws + WS_B1, nw2, nb2, ws + WS_B2,  256, 1024, 1024, 1024, 1024);
    k_gemm<false><<<grd, 256, 0, stream>>>(ws + WS_B2, nw3, nb3, ws + WS_VAR, 256, 1024, 1000, 1024, 1024);

    // ODE least-squares (exact recurrence + Neumann regularization correction) + all outputs
    k_ode<<<256, 256, 0, stream>>>(ws, out);
}

// Round 2
// 76.078 us; speedup vs baseline: 5.7202x; 5.7202x over previous
//
#include <hip/hip_runtime.h>
#include <math.h>

#define NN 1000

typedef _Float16 f16;
typedef _Float16 f16x8 __attribute__((ext_vector_type(8)));
typedef _Float16 f16x4 __attribute__((ext_vector_type(4)));
typedef float    f32x4 __attribute__((ext_vector_type(4)));

// ---------------- workspace offsets ----------------
// f32 units:
#define WS_H1P 0
#define WS_H1T 1024
#define WS_H2P 2048
#define WS_H2T 3072
#define WS_TS  4096
#define WS_XI  5120
#define WS_VAR 8192                 // f32 [256][1024], ends at float 270336
// f16 units (relative to (f16*)d_ws):
#define WF_A0  540672               // f16 [256][1024]
#define WF_H1  802816               // f16 [256][1024]
#define WF_H2  1064960              // f16 [256][1024]
#define WF_BT  1327104              // f16 [1024][1024] (reused for nw1/nw2/nw3)

// ---------------- output float offsets ----------------
#define O_X0    0
#define O_STEP  256000
#define O_EPS   511744
#define O_VAR   512000
#define O_TS    768000
#define O_ALPHA 1024000
#define O_BETA  1024256
#define O_POWR  1024512

// ================= conversions =================
__global__ __launch_bounds__(256) void k_conv_a(const float* __restrict__ in, f16* __restrict__ a0)
{
    int row = blockIdx.x;               // 256 rows
    int t = threadIdx.x;                // 250 full float4s per row (1000 = 250*4)
    float4 v = {0.f, 0.f, 0.f, 0.f};
    if (t < 250) v = ((const float4*)(in + row * 1000))[t];
    f16x4 h = {(f16)v.x, (f16)v.y, (f16)v.z, (f16)v.w};
    *(f16x4*)&a0[row * 1024 + t * 4] = h;
}

// W f32 [K0][NW] row-major -> BT f16 [1024][1024], BT[n][k] = W[k][n] (zero-padded)
__global__ __launch_bounds__(256) void k_conv_bt(const float* __restrict__ W, int K0, int NW,
                                                 f16* __restrict__ BT)
{
    __shared__ float T[32][33];
    int tx = threadIdx.x & 31, ty = threadIdx.x >> 5;
    int kt = blockIdx.x * 32, ntile = blockIdx.y * 32;
    #pragma unroll
    for (int i = 0; i < 4; ++i) {
        int k = kt + ty + i * 8, n = ntile + tx;
        T[ty + i * 8][tx] = (k < K0 && n < NW) ? W[k * NW + n] : 0.f;
    }
    __syncthreads();
    #pragma unroll
    for (int i = 0; i < 4; ++i) {
        int n = ntile + ty + i * 8, k = kt + tx;
        BT[n * 1024 + k] = (f16)T[tx][ty + i * 8];
    }
}

// ================= small MLPs (batch 1), p/t fused =================
__global__ __launch_bounds__(256) void k_l1(const float* __restrict__ pin, const float* __restrict__ pw1,
    const float* __restrict__ pb1, const float* __restrict__ ptime, const float* __restrict__ tw1,
    const float* __restrict__ tb1, float* __restrict__ ws)
{
    bool tp = blockIdx.x >= 4;
    const float* in = tp ? ptime : pin;
    const float* W  = tp ? tw1 : pw1;
    const float* B  = tp ? tb1 : pb1;
    float* out = ws + (tp ? WS_H1T : WS_H1P);
    int bx = blockIdx.x & 3;
    __shared__ float sin_[64];
    if (threadIdx.x < 64) sin_[threadIdx.x] = in[threadIdx.x];
    __syncthreads();
    int u = bx * 256 + threadIdx.x;
    float acc = B[u];
    #pragma unroll 16
    for (int k = 0; k < 64; ++k) acc += sin_[k] * W[k * 1024 + u];
    out[u] = fmaxf(acc, 0.f);
}

__global__ __launch_bounds__(256) void k_l2(const float* __restrict__ pw2, const float* __restrict__ pb2,
    const float* __restrict__ tw2, const float* __restrict__ tb2, float* __restrict__ ws)
{
    bool tp = blockIdx.x >= 64;
    const float* h = ws + (tp ? WS_H1T : WS_H1P);
    const float* W = tp ? tw2 : pw2;
    const float* B = tp ? tb2 : pb2;
    float* out = ws + (tp ? WS_H2T : WS_H2P);
    int u0 = (int)(blockIdx.x & 63) * 16;
    int tid = threadIdx.x, ul = tid & 15, kc = tid >> 4;
    const float* wp = W + u0 + ul;
    float acc = 0.f;
    int kbase = kc * 64;
    #pragma unroll 8
    for (int k = 0; k < 64; ++k) acc += h[kbase + k] * wp[(size_t)(kbase + k) * 1024];
    __shared__ float red[16][17];
    red[kc][ul] = acc; __syncthreads();
    for (int s = 8; s; s >>= 1) { if (kc < s) red[kc][ul] += red[kc + s][ul]; __syncthreads(); }
    if (tid < 16) out[u0 + tid] = fmaxf(red[0][tid] + B[u0 + tid], 0.f);
}

// blocks 0..63: ts head (16 outputs each); block 64: xi head
__global__ __launch_bounds__(256) void k_l3(const float* __restrict__ pw3, const float* __restrict__ pb3,
    const float* __restrict__ tw3, const float* __restrict__ tb3, float* __restrict__ ws, float* __restrict__ out)
{
    int tid = threadIdx.x;
    if (blockIdx.x == 64) {
        const float* h2p = ws + WS_H2P;
        float p[3] = {0.f, 0.f, 0.f};
        for (int k = tid; k < 1024; k += 256) {
            float h = h2p[k];
            p[0] += h * pw3[k * 3 + 0];
            p[1] += h * pw3[k * 3 + 1];
            p[2] += h * pw3[k * 3 + 2];
        }
        __shared__ float red[256];
        float xi[3];
        #pragma unroll
        for (int j = 0; j < 3; ++j) {
            red[tid] = p[j]; __syncthreads();
            for (int s = 128; s > 0; s >>= 1) {
                if (tid < s) red[tid] += red[tid + s];
                __syncthreads();
            }
            xi[j] = red[0] + pb3[j];
            __syncthreads();
        }
        float alpha = xi[0], beta = xi[1];
        float powr = 1.f / (1.f + expf(-xi[2]));
        if (tid == 0) { ws[WS_XI + 0] = alpha; ws[WS_XI + 1] = beta; ws[WS_XI + 2] = powr; }
        out[O_ALPHA + tid] = alpha;
        out[O_BETA  + tid] = beta;
        out[O_POWR  + tid] = powr;
    } else {
        const float* h = ws + WS_H2T;
        int u0 = blockIdx.x * 16;
        int ul = tid & 15, kc = tid >> 4;
        int u = u0 + ul;
        float acc = 0.f;
        int kbase = kc * 64;
        if (u < NN) {
            #pragma unroll 8
            for (int k = 0; k < 64; ++k) acc += h[kbase + k] * tw3[(size_t)(kbase + k) * NN + u];
        }
        __shared__ float red[16][17];
        red[kc][ul] = acc; __syncthreads();
        for (int s = 8; s; s >>= 1) { if (kc < s) red[kc][ul] += red[kc + s][ul]; __syncthreads(); }
        if (tid < 16 && u0 + tid < NN) ws[WS_TS + u0 + tid] = red[0][tid] + tb3[u0 + tid];
    }
}

// ================= f16 MFMA GEMM =================
// C(256x1024) = act(A(256x1024,f16) @ BT^T + bias), BT: f16 [1024 n][1024 k]
// grid (32 n-tiles, 8 m-tiles), 256 thr = 4 waves, wave tile 16x16, BK=64, dbuf LDS.
template<bool F16OUT>
__global__ __launch_bounds__(256) void k_gemm16(const f16* __restrict__ A, const f16* __restrict__ BT,
    const float* __restrict__ bias, int nbias, f16* __restrict__ Cf16, float* __restrict__ Cf32)
{
    __shared__ f16 As[2][32][72];     // 64 f16 + 8 pad (16B) per row
    __shared__ f16 Bs[2][32][72];
    const int tid = threadIdx.x;
    const int lane = tid & 63, wave = tid >> 6;
    const int wm = wave >> 1, wn = wave & 1;
    const int m0 = blockIdx.y * 32, n0 = blockIdx.x * 32;
    const int srow = tid >> 3, sc = tid & 7;                 // staging: 32 rows x 8 chunks
    const float4* gA = (const float4*)(A  + (size_t)(m0 + srow) * 1024 + sc * 8);
    const float4* gB = (const float4*)(BT + (size_t)(n0 + srow) * 1024 + sc * 8);

    f32x4 acc = {0.f, 0.f, 0.f, 0.f};

    float4 ra = gA[0], rb = gB[0];
    *(float4*)&As[0][srow][sc * 8] = ra;
    *(float4*)&Bs[0][srow][sc * 8] = rb;
    ra = gA[8]; rb = gB[8];                                  // tile 1 in flight
    __syncthreads();

    const int arow = wm * 16 + (lane & 15);
    const int brow = wn * 16 + (lane & 15);
    const int kf = (lane >> 4) * 8;

    #pragma unroll 2
    for (int t = 0; t < 16; ++t) {
        const int cur = t & 1;
        float4 ra2 = {}, rb2 = {};
        if (t + 2 < 16) { ra2 = gA[(t + 2) * 8]; rb2 = gB[(t + 2) * 8]; }

        const f16x8 a0 = *(const f16x8*)&As[cur][arow][kf];
        const f16x8 b0 = *(const f16x8*)&Bs[cur][brow][kf];
        acc = __builtin_amdgcn_mfma_f32_16x16x32_f16(a0, b0, acc, 0, 0, 0);
        const f16x8 a1 = *(const f16x8*)&As[cur][arow][32 + kf];
        const f16x8 b1 = *(const f16x8*)&Bs[cur][brow][32 + kf];
        acc = __builtin_amdgcn_mfma_f32_16x16x32_f16(a1, b1, acc, 0, 0, 0);

        __syncthreads();
        if (t + 1 < 16) {
            *(float4*)&As[cur ^ 1][srow][sc * 8] = ra;
            *(float4*)&Bs[cur ^ 1][srow][sc * 8] = rb;
        }
        ra = ra2; rb = rb2;
        __syncthreads();
    }

    // C/D layout: col = lane&15, row = (lane>>4)*4 + j   [measured m89/m91]
    const int col = n0 + wn * 16 + (lane & 15);
    const int row = m0 + wm * 16 + (lane >> 4) * 4;
    const float bs = (col < nbias) ? bias[col] : 0.f;
    #pragma unroll
    for (int j = 0; j < 4; ++j) {
        float v = acc[j] + bs;
        if (F16OUT) {
            v = fmaxf(v, 0.f);
            Cf16[(size_t)(row + j) * 1024 + col] = (f16)v;
        } else {
            Cf32[(size_t)(row + j) * 1024 + col] = v;
        }
    }
}

// ================= ODE solve (unchanged math, f64) =================
__device__ inline void d_shift_left(const double a[4], double b4[4], double* sh, int tid, double pad)
{
    __syncthreads();
    sh[tid] = a[0];
    __syncthreads();
    b4[0] = a[1]; b4[1] = a[2]; b4[2] = a[3];
    b4[3] = (tid < 255) ? sh[tid + 1] : pad;
}
__device__ inline void d_shift_right(const double a[4], double b4[4], double* sh, int tid, double pad)
{
    __syncthreads();
    sh[tid] = a[3];
    __syncthreads();
    b4[1] = a[0]; b4[2] = a[1]; b4[3] = a[2];
    b4[0] = (tid > 0) ? sh[tid - 1] : pad;
}
__device__ inline void d_scan_fwd(const double a[4], double incl[4], double* swt, int tid)
{
    double p0 = a[0], p1 = p0 + a[1], p2 = p1 + a[2], p3 = p2 + a[3];
    int lane = tid & 63, wid = tid >> 6;
    double w = p3;
    #pragma unroll
    for (int d = 1; d < 64; d <<= 1) {
        double t = __shfl_up(w, d, 64);
        if (lane >= d) w += t;
    }
    __syncthreads();
    if (lane == 63) swt[wid] = w;
    __syncthreads();
    double off = w - p3;
    #pragma unroll
    for (int q = 0; q < 3; ++q) if (q < wid) off += swt[q];
    incl[0] = p0 + off; incl[1] = p1 + off; incl[2] = p2 + off; incl[3] = p3 + off;
}
__device__ inline void d_scan_rev(const double a[4], double incl[4], double* swt, int tid)
{
    double s3 = a[3], s2 = s3 + a[2], s1 = s2 + a[1], s0 = s1 + a[0];
    int lane = tid & 63, wid = tid >> 6;
    double w = s0;
    #pragma unroll
    for (int d = 1; d < 64; d <<= 1) {
        double t = __shfl_down(w, d, 64);
        if (lane < 64 - d) w += t;
    }
    __syncthreads();
    if (lane == 0) swt[wid] = w;
    __syncthreads();
    double off = w - s0;
    #pragma unroll
    for (int q = 1; q < 4; ++q) if (q > wid) off += swt[q];
    incl[0] = s0 + off; incl[1] = s1 + off; incl[2] = s2 + off; incl[3] = s3 + off;
}

__global__ __launch_bounds__(256) void k_ode(const float* __restrict__ ws, float* __restrict__ out)
{
    const int b = blockIdx.x;
    const int tid = threadIdx.x;
    const double H = 0.001, H2c = 0.5e-6, INVH = 1000.0, EPSR = 1e-8;

    __shared__ double sh[257];
    __shared__ double swt[4];

    const float alpha = ws[WS_XI + 0], beta = ws[WS_XI + 1], powr = ws[WS_XI + 2];

    const float4 tsv = *(const float4*)&ws[WS_TS + tid * 4];
    const float4 vav = *(const float4*)&ws[WS_VAR + b * 1024 + tid * 4];
    const double init = (double)ws[WS_VAR + b * 1024];

    float tsa[4] = {tsv.x, tsv.y, tsv.z, tsv.w};
    float vaa[4] = {vav.x, vav.y, vav.z, vav.w};

    double r[4];
    #pragma unroll
    for (int k = 0; k < 4; ++k) {
        int i = tid * 4 + k;
        float tf = tsa[k], vf = vaa[k];
        float basef = fabsf(alpha * tf + beta * tf * tf);
        float rr = powf(basef, powr) * vf * vf + tf;
        r[k] = (i < NN) ? (double)rr : 0.0;
    }

    double rn[4];
    d_shift_left(r, rn, sh, tid, 0.0);
    double ux[4], ud[4], us[4], g[4], gi[4];
    #pragma unroll
    for (int k = 0; k < 4; ++k) {
        int i = tid * 4 + k;
        ud[k] = r[k];
        us[k] = (i < NN - 1) ? (rn[k] - r[k]) * INVH : 0.0;
        g[k]  = (i < NN - 1) ? 0.5 * H * (r[k] + rn[k]) : 0.0;
    }
    d_scan_fwd(g, gi, swt, tid);
    #pragma unroll
    for (int k = 0; k < 4; ++k) {
        int i = tid * 4 + k;
        ux[k] = (i < NN) ? (init + (gi[k] - g[k])) : 0.0;
    }

    double tx[4] = {0,0,0,0}, td[4] = {0,0,0,0}, tss[4] = {0,0,0,0};
    for (int it = 0; it < 8; ++it) {
        double a[4];
        #pragma unroll
        for (int k = 0; k < 4; ++k) {
            int i = tid * 4 + k;
            double yx = ux[k] - EPSR * tx[k];
            a[k] = (i == 0) ? 0.0 : yx;
        }
        double S[4]; d_scan_rev(a, S, swt, tid);
        double wP[4]; d_shift_left(S, wP, sh, tid, 0.0);
        __syncthreads();
        if (tid == 0) sh[256] = (ux[0] - EPSR * tx[0]) + wP[0];
        __syncthreads();
        double w0 = sh[256];
        double wV[4];
        #pragma unroll
        for (int k = 0; k < 4; ++k) {
            int i = tid * 4 + k;
            double ys = us[k] - EPSR * tss[k];
            wV[k] = (i < NN - 1) ? -(ys + H2c * wP[k]) * INVH : 0.0;
        }
        double wVm[4]; d_shift_right(wV, wVm, sh, tid, 0.0);
        double wD[4];
        #pragma unroll
        for (int k = 0; k < 4; ++k) {
            int i = tid * 4 + k;
            double yd = ud[k] - EPSR * td[k];
            wD[k] = (i < NN) ? (yd + ((i < NN - 1) ? H * wP[k] : 0.0) - wVm[k] + wV[k]) : 0.0;
        }
        double wDn[4]; d_shift_left(wD, wDn, sh, tid, 0.0);
        #pragma unroll
        for (int k = 0; k < 4; ++k) {
            int i = tid * 4 + k;
            td[k]  = wD[k];
            tss[k] = (i < NN - 1) ? (wDn[k] - wD[k] - wV[k]) * INVH : 0.0;
            g[k]   = (i < NN - 1) ? (H * td[k] + H2c * tss[k] + wP[k]) : 0.0;
        }
        d_scan_fwd(g, gi, swt, tid);
        #pragma unroll
        for (int k = 0; k < 4; ++k) {
            int i = tid * 4 + k;
            tx[k] = (i < NN) ? (w0 + (gi[k] - g[k])) : 0.0;
        }
    }

    double dx[4], dd[4], ds_[4];
    #pragma unroll
    for (int k = 0; k < 4; ++k) { dx[k] = -EPSR * tx[k]; dd[k] = -EPSR * td[k]; ds_[k] = -EPSR * tss[k]; }

    #pragma unroll
    for (int k = 0; k < 4; ++k) {
        int i = tid * 4 + k;
        if (i < NN) {
            out[O_X0  + b * NN + i] = (float)(ux[k] + dx[k]);
            out[O_VAR + b * NN + i] = vaa[k];
            out[O_TS  + b * NN + i] = tsa[k];
        }
        if (i < NN - 1) out[O_STEP + b * (NN - 1) + i] = 0.001f;
    }
    if (tid == 0) { out[O_ALPHA + b] = alpha; out[O_BETA + b] = beta; out[O_POWR + b] = powr; }

    double dxn[4], ddn[4];
    d_shift_left(dx, dxn, sh, tid, 0.0);
    d_shift_left(dd, ddn, sh, tid, 0.0);
    double ss = 0.0;
    #pragma unroll
    for (int k = 0; k < 4; ++k) {
        int i = tid * 4 + k;
        if (i < NN) ss += dd[k] * dd[k];
        if (i == 0) ss += dx[k] * dx[k];
        if (i < NN - 1) {
            double rp = dxn[k] - dx[k] - H * dd[k] - H2c * ds_[k];
            double rv = ddn[k] - dd[k] - H * ds_[k];
            ss += rp * rp + rv * rv;
        }
    }
    __syncthreads();
    sh[tid] = ss;
    __syncthreads();
    for (int s = 128; s > 0; s >>= 1) {
        if (tid < s) sh[tid] += sh[tid + s];
        __syncthreads();
    }
    if (tid == 0) out[O_EPS + b] = (float)sqrt(sh[0]);
}

// ================= launcher =================
extern "C" void kernel_launch(void* const* d_in, const int* in_sizes, int n_in,
                              void* d_out, int out_size, void* d_ws, size_t ws_size,
                              hipStream_t stream)
{
    const float* pin    = (const float*)d_in[0];
    const float* ptime  = (const float*)d_in[1];
    const float* pw1    = (const float*)d_in[2];
    const float* pb1    = (const float*)d_in[3];
    const float* pw2    = (const float*)d_in[4];
    const float* pb2    = (const float*)d_in[5];
    const float* pw3    = (const float*)d_in[6];
    const float* pb3    = (const float*)d_in[7];
    const float* tw1    = (const float*)d_in[8];
    const float* tb1    = (const float*)d_in[9];
    const float* tw2    = (const float*)d_in[10];
    const float* tb2    = (const float*)d_in[11];
    const float* tw3    = (const float*)d_in[12];
    const float* tb3    = (const float*)d_in[13];
    const float* nw1    = (const float*)d_in[14];
    const float* nb1    = (const float*)d_in[15];
    const float* nw2    = (const float*)d_in[16];
    const float* nb2    = (const float*)d_in[17];
    const float* nw3    = (const float*)d_in[18];
    const float* nb3    = (const float*)d_in[19];
    const float* net_iv = (const float*)d_in[20];
    float* out = (float*)d_out;
    float* ws  = (float*)d_ws;
    f16*   wsh = (f16*)d_ws;

    dim3 tg(32, 32);
    dim3 gg(32, 8);

    // conversions for gemm1
    k_conv_a<<<256, 256, 0, stream>>>(net_iv, wsh + WF_A0);
    k_conv_bt<<<tg, 256, 0, stream>>>(nw1, 1000, 1024, wsh + WF_BT);

    // small MLP chain (p & t fused)
    k_l1<<<8, 256, 0, stream>>>(pin, pw1, pb1, ptime, tw1, tb1, ws);
    k_l2<<<128, 256, 0, stream>>>(pw2, pb2, tw2, tb2, ws);
    k_l3<<<65, 256, 0, stream>>>(pw3, pb3, tw3, tb3, ws, out);

    // var MLP: f16 MFMA GEMMs with B^T conversion interleaved (BT buffer reused)
    k_gemm16<true ><<<gg, 256, 0, stream>>>(wsh + WF_A0, wsh + WF_BT, nb1, 1024, wsh + WF_H1, nullptr);
    k_conv_bt<<<tg, 256, 0, stream>>>(nw2, 1024, 1024, wsh + WF_BT);
    k_gemm16<true ><<<gg, 256, 0, stream>>>(wsh + WF_H1, wsh + WF_BT, nb2, 1024, wsh + WF_H2, nullptr);
    k_conv_bt<<<tg, 256, 0, stream>>>(nw3, 1024, 1000, wsh + WF_BT);
    k_gemm16<false><<<gg, 256, 0, stream>>>(wsh + WF_H2, wsh + WF_BT, nb3, 1000, nullptr, ws + WS_VAR);

    // ODE least-squares + all outputs
    k_ode<<<256, 256, 0, stream>>>(ws, out);
}

// Round 3
// 47.815 us; speedup vs baseline: 9.1013x; 1.5911x over previous
//
#include <hip/hip_runtime.h>
#include <math.h>

#define NN 1000
#define NIT 6

typedef _Float16 f16;
typedef _Float16 f16x8 __attribute__((ext_vector_type(8)));
typedef _Float16 f16x4 __attribute__((ext_vector_type(4)));
typedef float    f32x4 __attribute__((ext_vector_type(4)));

// ---------------- workspace offsets ----------------
// f32 units:
#define WS_H1P 0
#define WS_H1T 1024
#define WS_H2P 2048
#define WS_H2T 3072
#define WS_TS  4096
#define WS_XI  5120
#define WS_VAR 8192                 // f32 [256][1024], ends at float 270336
// f16 units (relative to (f16*)d_ws):
#define WF_A0  540672               // f16 [256][1024]
#define WF_H1  802816               // f16 [256][1024]
#define WF_H2  1064960              // f16 [256][1024]
#define WF_BT1 1327104              // f16 [1024][1024]
#define WF_BT2 2375680
#define WF_BT3 3424256

// ---------------- output float offsets ----------------
#define O_X0    0
#define O_STEP  256000
#define O_EPS   511744
#define O_VAR   512000
#define O_TS    768000
#define O_ALPHA 1024000
#define O_BETA  1024256
#define O_POWR  1024512

// ================= K1: conversions + l1 =================
// blocks 0..3071: conv_bt (3 matrices x 1024 tiles); 3072..3327: conv_a; 3328..3335: l1
__global__ __launch_bounds__(256) void k_stage1(
    const float* __restrict__ nw1, const float* __restrict__ nw2, const float* __restrict__ nw3,
    const float* __restrict__ net_iv,
    const float* __restrict__ pin, const float* __restrict__ pw1, const float* __restrict__ pb1,
    const float* __restrict__ ptime, const float* __restrict__ tw1, const float* __restrict__ tb1,
    float* __restrict__ ws, f16* __restrict__ wsh)
{
    __shared__ float T[32][33];
    __shared__ float sin_[64];
    const int bx = blockIdx.x;
    const int tid = threadIdx.x;
    if (bx < 3072) {
        const int m = bx >> 10, idx = bx & 1023;
        const float* W = (m == 0) ? nw1 : (m == 1) ? nw2 : nw3;
        const int K0 = (m == 0) ? 1000 : 1024;
        const int NW = (m == 2) ? 1000 : 1024;
        f16* BT = wsh + ((m == 0) ? WF_BT1 : (m == 1) ? WF_BT2 : WF_BT3);
        const int kt = (idx & 31) * 32, ntile = (idx >> 5) * 32;
        const int tx = tid & 31, ty = tid >> 5;
        #pragma unroll
        for (int i = 0; i < 4; ++i) {
            int k = kt + ty + i * 8, n = ntile + tx;
            T[ty + i * 8][tx] = (k < K0 && n < NW) ? W[(size_t)k * NW + n] : 0.f;
        }
        __syncthreads();
        #pragma unroll
        for (int i = 0; i < 4; ++i) {
            int n = ntile + ty + i * 8, k = kt + tx;
            BT[(size_t)n * 1024 + k] = (f16)T[tx][ty + i * 8];
        }
    } else if (bx < 3328) {
        const int row = bx - 3072;
        float4 v = {0.f, 0.f, 0.f, 0.f};
        if (tid < 250) v = ((const float4*)(net_iv + row * 1000))[tid];
        f16x4 h = {(f16)v.x, (f16)v.y, (f16)v.z, (f16)v.w};
        *(f16x4*)&wsh[WF_A0 + row * 1024 + tid * 4] = h;
    } else {
        const int sub = bx - 3328;
        const bool tp = sub >= 4;
        const float* in = tp ? ptime : pin;
        const float* W  = tp ? tw1 : pw1;
        const float* B  = tp ? tb1 : pb1;
        float* outp = ws + (tp ? WS_H1T : WS_H1P);
        const int bxl = sub & 3;
        if (tid < 64) sin_[tid] = in[tid];
        __syncthreads();
        const int u = bxl * 256 + tid;
        float acc = B[u];
        #pragma unroll 16
        for (int k = 0; k < 64; ++k) acc += sin_[k] * W[k * 1024 + u];
        outp[u] = fmaxf(acc, 0.f);
    }
}

// ================= GEMM body (f16 MFMA) =================
// C(256x1024) = act(A @ BT^T + bias); one block = 32x32 tile, 4 waves, BK=64, dbuf LDS.
template<bool F16OUT>
__device__ __forceinline__ void gemm_body(int bx, const f16* __restrict__ A, const f16* __restrict__ BT,
    const float* __restrict__ bias, int nbias, f16* __restrict__ Cf16, float* __restrict__ Cf32,
    f16 (*As)[32][72], f16 (*Bs)[32][72])
{
    const int tid = threadIdx.x;
    const int lane = tid & 63, wave = tid >> 6;
    const int wm = wave >> 1, wn = wave & 1;
    const int m0 = (bx >> 5) * 32, n0 = (bx & 31) * 32;
    const int srow = tid >> 3, sc = tid & 7;
    const float4* gA = (const float4*)(A  + (size_t)(m0 + srow) * 1024 + sc * 8);
    const float4* gB = (const float4*)(BT + (size_t)(n0 + srow) * 1024 + sc * 8);

    f32x4 acc = {0.f, 0.f, 0.f, 0.f};

    float4 ra = gA[0], rb = gB[0];
    *(float4*)&As[0][srow][sc * 8] = ra;
    *(float4*)&Bs[0][srow][sc * 8] = rb;
    ra = gA[8]; rb = gB[8];
    __syncthreads();

    const int arow = wm * 16 + (lane & 15);
    const int brow = wn * 16 + (lane & 15);
    const int kf = (lane >> 4) * 8;

    #pragma unroll 2
    for (int t = 0; t < 16; ++t) {
        const int cur = t & 1;
        float4 ra2 = {}, rb2 = {};
        if (t + 2 < 16) { ra2 = gA[(t + 2) * 8]; rb2 = gB[(t + 2) * 8]; }

        const f16x8 a0 = *(const f16x8*)&As[cur][arow][kf];
        const f16x8 b0 = *(const f16x8*)&Bs[cur][brow][kf];
        acc = __builtin_amdgcn_mfma_f32_16x16x32_f16(a0, b0, acc, 0, 0, 0);
        const f16x8 a1 = *(const f16x8*)&As[cur][arow][32 + kf];
        const f16x8 b1 = *(const f16x8*)&Bs[cur][brow][32 + kf];
        acc = __builtin_amdgcn_mfma_f32_16x16x32_f16(a1, b1, acc, 0, 0, 0);

        __syncthreads();
        if (t + 1 < 16) {
            *(float4*)&As[cur ^ 1][srow][sc * 8] = ra;
            *(float4*)&Bs[cur ^ 1][srow][sc * 8] = rb;
        }
        ra = ra2; rb = rb2;
        __syncthreads();
    }

    const int col = n0 + wn * 16 + (lane & 15);
    const int row = m0 + wm * 16 + (lane >> 4) * 4;
    const float bs = (col < nbias) ? bias[col] : 0.f;
    #pragma unroll
    for (int j = 0; j < 4; ++j) {
        float v = acc[j] + bs;
        if (F16OUT) {
            v = fmaxf(v, 0.f);
            Cf16[(size_t)(row + j) * 1024 + col] = (f16)v;
        } else {
            Cf32[(size_t)(row + j) * 1024 + col] = v;
        }
    }
}

// ================= l2 body (batch-1 GEMV, 1024->1024) =================
__device__ __forceinline__ void l2_body(int lb, const float* __restrict__ pw2, const float* __restrict__ pb2,
    const float* __restrict__ tw2, const float* __restrict__ tb2, float* __restrict__ ws,
    float (*red)[16][17])
{
    const bool tp = lb >= 64;
    const float* h = ws + (tp ? WS_H1T : WS_H1P);
    const float* W = tp ? tw2 : pw2;
    const float* B = tp ? tb2 : pb2;
    float* outp = ws + (tp ? WS_H2T : WS_H2P);
    const int u0 = (lb & 63) * 16;
    const int tid = threadIdx.x, ul = tid & 15, kc = tid >> 4;
    const float* wp = W + u0 + ul;
    float acc = 0.f;
    const int kbase = kc * 64;
    #pragma unroll 8
    for (int k = 0; k < 64; ++k) acc += h[kbase + k] * wp[(size_t)(kbase + k) * 1024];
    (*red)[kc][ul] = acc; __syncthreads();
    for (int s = 8; s; s >>= 1) { if (kc < s) (*red)[kc][ul] += (*red)[kc + s][ul]; __syncthreads(); }
    if (tid < 16) outp[u0 + tid] = fmaxf((*red)[0][tid] + B[u0 + tid], 0.f);
}

// ================= K2: gemm1 + l2 =================
__global__ __launch_bounds__(256) void k_stage2(const float* __restrict__ pw2, const float* __restrict__ pb2,
    const float* __restrict__ tw2, const float* __restrict__ tb2,
    const float* __restrict__ nb1, float* __restrict__ ws, f16* __restrict__ wsh)
{
    __shared__ f16 As[2][32][72];
    __shared__ f16 Bs[2][32][72];
    __shared__ float red[16][17];
    const int bx = blockIdx.x;
    if (bx < 256) {
        gemm_body<true>(bx, wsh + WF_A0, wsh + WF_BT1, nb1, 1024, wsh + WF_H1, nullptr, As, Bs);
    } else {
        l2_body(bx - 256, pw2, pb2, tw2, tb2, ws, &red);
    }
}

// ================= K3: gemm2 + l3/xi =================
__global__ __launch_bounds__(256) void k_stage3(const float* __restrict__ pw3, const float* __restrict__ pb3,
    const float* __restrict__ tw3, const float* __restrict__ tb3,
    const float* __restrict__ nb2, float* __restrict__ ws, f16* __restrict__ wsh, float* __restrict__ out)
{
    __shared__ f16 As[2][32][72];
    __shared__ f16 Bs[2][32][72];
    __shared__ float red[16][17];
    __shared__ float redx[256];
    const int bx = blockIdx.x;
    const int tid = threadIdx.x;
    if (bx < 256) {
        gemm_body<true>(bx, wsh + WF_H1, wsh + WF_BT2, nb2, 1024, wsh + WF_H2, nullptr, As, Bs);
    } else if (bx == 256 + 64) {
        const float* h2p = ws + WS_H2P;
        float p[3] = {0.f, 0.f, 0.f};
        for (int k = tid; k < 1024; k += 256) {
            float h = h2p[k];
            p[0] += h * pw3[k * 3 + 0];
            p[1] += h * pw3[k * 3 + 1];
            p[2] += h * pw3[k * 3 + 2];
        }
        float xi[3];
        #pragma unroll
        for (int j = 0; j < 3; ++j) {
            redx[tid] = p[j]; __syncthreads();
            for (int s = 128; s > 0; s >>= 1) {
                if (tid < s) redx[tid] += redx[tid + s];
                __syncthreads();
            }
            xi[j] = redx[0] + pb3[j];
            __syncthreads();
        }
        float alpha = xi[0], beta = xi[1];
        float powr = 1.f / (1.f + expf(-xi[2]));
        if (tid == 0) { ws[WS_XI + 0] = alpha; ws[WS_XI + 1] = beta; ws[WS_XI + 2] = powr; }
        out[O_ALPHA + tid] = alpha;
        out[O_BETA  + tid] = beta;
        out[O_POWR  + tid] = powr;
    } else {
        const int lb = bx - 256;                       // 0..63: ts head
        const float* h = ws + WS_H2T;
        const int u0 = lb * 16;
        const int ul = tid & 15, kc = tid >> 4;
        const int u = u0 + ul;
        float acc = 0.f;
        const int kbase = kc * 64;
        if (u < NN) {
            #pragma unroll 8
            for (int k = 0; k < 64; ++k) acc += h[kbase + k] * tw3[(size_t)(kbase + k) * NN + u];
        }
        red[kc][ul] = acc; __syncthreads();
        for (int s = 8; s; s >>= 1) { if (kc < s) red[kc][ul] += red[kc + s][ul]; __syncthreads(); }
        if (tid < 16 && u0 + tid < NN) ws[WS_TS + u0 + tid] = red[0][tid] + tb3[u0 + tid];
    }
}

// ================= K4: gemm3 =================
__global__ __launch_bounds__(256) void k_stage4(const float* __restrict__ nb3,
    float* __restrict__ ws, f16* __restrict__ wsh)
{
    __shared__ f16 As[2][32][72];
    __shared__ f16 Bs[2][32][72];
    gemm_body<false>(blockIdx.x, wsh + WF_H2, wsh + WF_BT3, nb3, 1000, nullptr, ws + WS_VAR, As, Bs);
}

// ================= K5: ODE solve (f64, reduced barrier count) =================
__device__ inline void d_shift_left(const double a[4], double b4[4], double* sh, int tid, double pad)
{
    __syncthreads();
    sh[tid] = a[0];
    __syncthreads();
    b4[0] = a[1]; b4[1] = a[2]; b4[2] = a[3];
    b4[3] = (tid < 255) ? sh[tid + 1] : pad;
}
__device__ inline void d_scan_fwd(const double a[4], double incl[4], double* swt, int tid)
{
    double p0 = a[0], p1 = p0 + a[1], p2 = p1 + a[2], p3 = p2 + a[3];
    int lane = tid & 63, wid = tid >> 6;
    double w = p3;
    #pragma unroll
    for (int d = 1; d < 64; d <<= 1) {
        double t = __shfl_up(w, d, 64);
        if (lane >= d) w += t;
    }
    __syncthreads();
    if (lane == 63) swt[wid] = w;
    __syncthreads();
    double off = w - p3;
    #pragma unroll
    for (int q = 0; q < 3; ++q) if (q < wid) off += swt[q];
    incl[0] = p0 + off; incl[1] = p1 + off; incl[2] = p2 + off; incl[3] = p3 + off;
}
__device__ inline void d_scan_rev(const double a[4], double incl[4], double* swt, int tid)
{
    double s3 = a[3], s2 = s3 + a[2], s1 = s2 + a[1], s0 = s1 + a[0];
    int lane = tid & 63, wid = tid >> 6;
    double w = s0;
    #pragma unroll
    for (int d = 1; d < 64; d <<= 1) {
        double t = __shfl_down(w, d, 64);
        if (lane < 64 - d) w += t;
    }
    __syncthreads();
    if (lane == 0) swt[wid] = w;
    __syncthreads();
    double off = w - s0;
    #pragma unroll
    for (int q = 1; q < 4; ++q) if (q > wid) off += swt[q];
    incl[0] = s0 + off; incl[1] = s1 + off; incl[2] = s2 + off; incl[3] = s3 + off;
}

__global__ __launch_bounds__(256) void k_ode(const float* __restrict__ ws, float* __restrict__ out)
{
    const int b = blockIdx.x;
    const int tid = threadIdx.x;
    const double H = 0.001, H2c = 0.5e-6, INVH = 1000.0, EPSR = 1e-8;

    __shared__ double sh[257];
    __shared__ double swt[4];

    const float alpha = ws[WS_XI + 0], beta = ws[WS_XI + 1], powr = ws[WS_XI + 2];

    const float4 tsv = *(const float4*)&ws[WS_TS + tid * 4];
    const float4 vav = *(const float4*)&ws[WS_VAR + b * 1024 + tid * 4];
    const double init = (double)ws[WS_VAR + b * 1024];

    float tsa[4] = {tsv.x, tsv.y, tsv.z, tsv.w};
    float vaa[4] = {vav.x, vav.y, vav.z, vav.w};

    double r[4];
    #pragma unroll
    for (int k = 0; k < 4; ++k) {
        int i = tid * 4 + k;
        float tf = tsa[k], vf = vaa[k];
        float basef = fabsf(alpha * tf + beta * tf * tf);
        float rr = powf(basef, powr) * vf * vf + tf;
        r[k] = (i < NN) ? (double)rr : 0.0;
    }

    double rn[4];
    d_shift_left(r, rn, sh, tid, 0.0);
    double ux[4], ud[4], us[4], g[4], gi[4];
    #pragma unroll
    for (int k = 0; k < 4; ++k) {
        int i = tid * 4 + k;
        ud[k] = r[k];
        us[k] = (i < NN - 1) ? (rn[k] - r[k]) * INVH : 0.0;
        g[k]  = (i < NN - 1) ? 0.5 * H * (r[k] + rn[k]) : 0.0;
    }
    d_scan_fwd(g, gi, swt, tid);
    #pragma unroll
    for (int k = 0; k < 4; ++k) {
        int i = tid * 4 + k;
        ux[k] = (i < NN) ? (init + (gi[k] - g[k])) : 0.0;
    }

    double tx[4] = {0,0,0,0}, td[4] = {0,0,0,0}, tss[4] = {0,0,0,0};
    for (int it = 0; it < NIT; ++it) {
        double a[4], yx0 = 0.0;
        #pragma unroll
        for (int k = 0; k < 4; ++k) {
            int i = tid * 4 + k;
            double yx = ux[k] - EPSR * tx[k];
            if (k == 0) yx0 = yx;
            a[k] = (i == 0) ? 0.0 : yx;
        }
        double S[4]; d_scan_rev(a, S, swt, tid);
        double wP[4];
        #pragma unroll
        for (int k = 0; k < 4; ++k) wP[k] = S[k] - a[k];   // reverse-EXCLUSIVE: sum_{j>i}
        double wV[4];
        #pragma unroll
        for (int k = 0; k < 4; ++k) {
            int i = tid * 4 + k;
            double ys = us[k] - EPSR * tss[k];
            wV[k] = (i < NN - 1) ? -(ys + H2c * wP[k]) * INVH : 0.0;
        }
        // shift_right(wV) with w0 broadcast piggybacked on same sync pair
        __syncthreads();
        sh[tid] = wV[3];
        if (tid == 0) sh[256] = yx0 + wP[0];
        __syncthreads();
        double wVm[4];
        wVm[1] = wV[0]; wVm[2] = wV[1]; wVm[3] = wV[2];
        wVm[0] = (tid > 0) ? sh[tid - 1] : 0.0;
        const double w0 = sh[256];

        double wD[4];
        #pragma unroll
        for (int k = 0; k < 4; ++k) {
            int i = tid * 4 + k;
            double yd = ud[k] - EPSR * td[k];
            wD[k] = (i < NN) ? (yd + ((i < NN - 1) ? H * wP[k] : 0.0) - wVm[k] + wV[k]) : 0.0;
        }
        double wDn[4]; d_shift_left(wD, wDn, sh, tid, 0.0);
        #pragma unroll
        for (int k = 0; k < 4; ++k) {
            int i = tid * 4 + k;
            td[k]  = wD[k];
            tss[k] = (i < NN - 1) ? (wDn[k] - wD[k] - wV[k]) * INVH : 0.0;
            g[k]   = (i < NN - 1) ? (H * td[k] + H2c * tss[k] + wP[k]) : 0.0;
        }
        d_scan_fwd(g, gi, swt, tid);
        #pragma unroll
        for (int k = 0; k < 4; ++k) {
            int i = tid * 4 + k;
            tx[k] = (i < NN) ? (w0 + (gi[k] - g[k])) : 0.0;
        }
    }

    double dx[4], dd[4], ds_[4];
    #pragma unroll
    for (int k = 0; k < 4; ++k) { dx[k] = -EPSR * tx[k]; dd[k] = -EPSR * td[k]; ds_[k] = -EPSR * tss[k]; }

    #pragma unroll
    for (int k = 0; k < 4; ++k) {
        int i = tid * 4 + k;
        if (i < NN) {
            out[O_X0  + b * NN + i] = (float)(ux[k] + dx[k]);
            out[O_VAR + b * NN + i] = vaa[k];
            out[O_TS  + b * NN + i] = tsa[k];
        }
        if (i < NN - 1) out[O_STEP + b * (NN - 1) + i] = 0.001f;
    }

    double dxn[4], ddn[4];
    d_shift_left(dx, dxn, sh, tid, 0.0);
    d_shift_left(dd, ddn, sh, tid, 0.0);
    double ss = 0.0;
    #pragma unroll
    for (int k = 0; k < 4; ++k) {
        int i = tid * 4 + k;
        if (i < NN) ss += dd[k] * dd[k];
        if (i == 0) ss += dx[k] * dx[k];
        if (i < NN - 1) {
            double rp = dxn[k] - dx[k] - H * dd[k] - H2c * ds_[k];
            double rv = ddn[k] - dd[k] - H * ds_[k];
            ss += rp * rp + rv * rv;
        }
    }
    // wave reduce then 4 partials
    const int lane = tid & 63, wid = tid >> 6;
    #pragma unroll
    for (int d = 32; d; d >>= 1) ss += __shfl_down(ss, d, 64);
    __syncthreads();
    if (lane == 0) swt[wid] = ss;
    __syncthreads();
    if (tid == 0) out[O_EPS + b] = (float)sqrt(swt[0] + swt[1] + swt[2] + swt[3]);
}

// ================= launcher =================
extern "C" void kernel_launch(void* const* d_in, const int* in_sizes, int n_in,
                              void* d_out, int out_size, void* d_ws, size_t ws_size,
                              hipStream_t stream)
{
    const float* pin    = (const float*)d_in[0];
    const float* ptime  = (const float*)d_in[1];
    const float* pw1    = (const float*)d_in[2];
    const float* pb1    = (const float*)d_in[3];
    const float* pw2    = (const float*)d_in[4];
    const float* pb2    = (const float*)d_in[5];
    const float* pw3    = (const float*)d_in[6];
    const float* pb3    = (const float*)d_in[7];
    const float* tw1    = (const float*)d_in[8];
    const float* tb1    = (const float*)d_in[9];
    const float* tw2    = (const float*)d_in[10];
    const float* tb2    = (const float*)d_in[11];
    const float* tw3    = (const float*)d_in[12];
    const float* tb3    = (const float*)d_in[13];
    const float* nw1    = (const float*)d_in[14];
    const float* nb1    = (const float*)d_in[15];
    const float* nw2    = (const float*)d_in[16];
    const float* nb2    = (const float*)d_in[17];
    const float* nw3    = (const float*)d_in[18];
    const float* nb3    = (const float*)d_in[19];
    const float* net_iv = (const float*)d_in[20];
    float* out = (float*)d_out;
    float* ws  = (float*)d_ws;
    f16*   wsh = (f16*)d_ws;

    k_stage1<<<3336, 256, 0, stream>>>(nw1, nw2, nw3, net_iv, pin, pw1, pb1, ptime, tw1, tb1, ws, wsh);
    k_stage2<<<384,  256, 0, stream>>>(pw2, pb2, tw2, tb2, nb1, ws, wsh);
    k_stage3<<<321,  256, 0, stream>>>(pw3, pb3, tw3, tb3, nb2, ws, wsh, out);
    k_stage4<<<256,  256, 0, stream>>>(nb3, ws, wsh);
    k_ode   <<<256,  256, 0, stream>>>(ws, out);
}